// Round 11
// baseline (252.862 us; speedup 1.0000x reference)
//
#include <hip/hip_runtime.h>

// GCN encoder, CSR-free aggregation with separable norm + bf16 gather tables.
//   dinv[i] = rsqrt(deg_in[i]+1)
//   T1 = bf16( dinv * (x@W1) )                       [MFMA gemm1, fused scale+quant]
//   T2 = bf16( dinv * relu( dinv*aggsum(T1) + b1 ) ) [agg<0>]
//   T3 = bf16( dinv * aggsum(T2) )                   [agg<1>, reuses T1 buffer]
//   mu = T3@Wmu+bmu ; ls = T3@Wls+bls                [MFMA dual gemm]
// Edges are bucket-sorted (256-node buckets) into bpk; each agg block owns one
// bucket and rebuilds its node-level CSR in LDS (count->scan->scatter) -- this
// work hides under gather-service stalls, replacing the low-occupancy place
// kernel and all global ssrc/rowptr traffic. deg counting is fused into hist.
// Lessons kept: no global-cursor atomics (R4), no interleaved feature slices
// (R7), no cooperative mega-kernel (R9), sort regions stay 64B (R3).
// aggs are at the compulsory fabric floor (~86MB = 8 XCDs x table once).

using uint = unsigned int;

static constexpr int FEAT = 64;
static constexpr int BN = 256;          // nodes per bucket (dlocal = 8 bits)
static constexpr int SORT_BLOCKS = 256; // edge chunks (keeps 64B sort regions)
static constexpr int NB_MAX = 512;      // max buckets supported in LDS
static constexpr int AGG_TPB = 1024;    // agg block = 16 waves
static constexpr int ECAP = 5120;       // bucket edge cap (mean 4096 + 16 sigma)

typedef __attribute__((ext_vector_type(8))) short bf16x8;
typedef __attribute__((ext_vector_type(4))) float f32x4;

static __device__ __forceinline__ ushort f2bf(float f) {
    uint u = __float_as_uint(f);
    u += 0x7FFFu + ((u >> 16) & 1u);
    return (ushort)(u >> 16);
}
static __device__ __forceinline__ float bf2f(ushort b) {
    return __uint_as_float(((uint)b) << 16);
}

// ---------------- CSR-lite build ----------------

// hist + fused per-node degree count (deg pre-zeroed).
__global__ __launch_bounds__(256) void hist_kernel(const int* __restrict__ dst,
                                                   int* __restrict__ hist,
                                                   int* __restrict__ deg, int E, int nb) {
    __shared__ int h[NB_MAX];
    for (int i = threadIdx.x; i < nb; i += 256) h[i] = 0;
    __syncthreads();
    int chunk = (E + SORT_BLOCKS - 1) / SORT_BLOCKS;
    int beg = blockIdx.x * chunk;
    int end = min(beg + chunk, E);
    for (int e = beg + (int)threadIdx.x; e < end; e += 256) {
        int d = dst[e];
        atomicAdd(&h[d >> 8], 1);
        atomicAdd(&deg[d], 1);          // fire-and-forget, L2-side
    }
    __syncthreads();
    for (int i = threadIdx.x; i < nb; i += 256) hist[blockIdx.x * nb + i] = h[i];
}

__global__ __launch_bounds__(256) void dinv_kernel(const int* __restrict__ deg,
                                                   float* __restrict__ dinv, int n) {
    int i = blockIdx.x * 256 + threadIdx.x;
    if (i < n) dinv[i] = rsqrtf((float)deg[i] + 1.0f);
}

__global__ __launch_bounds__(256) void colscan_kernel(int* __restrict__ hist,
                                                      int* __restrict__ btot, int nb) {
    __shared__ int s[256];
    int b = blockIdx.x;
    int t = threadIdx.x;
    int v = hist[t * nb + b];
    s[t] = v; __syncthreads();
    for (int off = 1; off < 256; off <<= 1) {
        int u = (t >= off) ? s[t - off] : 0;
        __syncthreads();
        s[t] += u;
        __syncthreads();
    }
    hist[t * nb + b] = s[t] - v;      // exclusive within bucket
    if (t == 255) btot[b] = s[255];
}

__global__ __launch_bounds__(256) void bbase_kernel(const int* __restrict__ btot,
                                                    int* __restrict__ bbase, int nb) {
    __shared__ int s[256];
    int t = threadIdx.x;
    int i0 = 2 * t, i1 = 2 * t + 1;
    int v0 = (i0 < nb) ? btot[i0] : 0;
    int v1 = (i1 < nb) ? btot[i1] : 0;
    s[t] = v0 + v1; __syncthreads();
    for (int off = 1; off < 256; off <<= 1) {
        int u = (t >= off) ? s[t - off] : 0;
        __syncthreads();
        s[t] += u;
        __syncthreads();
    }
    int excl = s[t] - (v0 + v1);
    if (i0 <= nb) bbase[i0] = excl;
    if (i1 <= nb) bbase[i1] = excl + v0;
}

__global__ __launch_bounds__(256) void sort_scatter_kernel(const int* __restrict__ src,
                                                           const int* __restrict__ dst,
                                                           const int* __restrict__ hist,
                                                           const int* __restrict__ bbase,
                                                           uint* __restrict__ bpk, int E, int nb) {
    __shared__ int cur[NB_MAX];
    int k = blockIdx.x;
    for (int i = threadIdx.x; i < nb; i += 256) cur[i] = bbase[i] + hist[k * nb + i];
    __syncthreads();
    int chunk = (E + SORT_BLOCKS - 1) / SORT_BLOCKS;
    int beg = k * chunk;
    int end = min(beg + chunk, E);
    for (int e = beg + (int)threadIdx.x; e < end; e += 256) {
        int s = src[e], d = dst[e];
        int pos = atomicAdd(&cur[d >> 8], 1);
        bpk[pos] = (uint)s | ((uint)(d & 255) << 17);
    }
}

// ---------------- weight prep: transpose + bf16 ----------------
__global__ __launch_bounds__(256) void prep_w_kernel(const float* __restrict__ W1,
                                                     const float* __restrict__ Wmu,
                                                     const float* __restrict__ Wls,
                                                     ushort* __restrict__ w1t,
                                                     ushort* __restrict__ wmt,
                                                     ushort* __restrict__ wlt) {
    int t = blockIdx.x * 256 + threadIdx.x;
    for (int idx = t; idx < 64 * 128; idx += 2048) {
        int nn = idx >> 7, kk = idx & 127;
        w1t[idx] = f2bf(W1[kk * 64 + nn]);
    }
    for (int idx = t; idx < 64 * 64; idx += 2048) {
        int nn = idx >> 6, kk = idx & 63;
        wmt[idx] = f2bf(Wmu[kk * 64 + nn]);
        wlt[idx] = f2bf(Wls[kk * 64 + nn]);
    }
}

// ---------------- MFMA gemm1: T1 = bf16(dinv * (X@W1)) ----------------
__global__ __launch_bounds__(256) void gemm1_kernel(const float* __restrict__ X,
                                                    const ushort* __restrict__ Wt,
                                                    const float* __restrict__ dinv,
                                                    ushort* __restrict__ T1, int n) {
    int lane = threadIdx.x & 63;
    int w = threadIdx.x >> 6;
    int rowbase = blockIdx.x * 64 + w * 16;
    int nl = lane & 15;
    int kg = lane >> 4;
    int arow = min(rowbase + nl, n - 1);
    const float* xr = X + (size_t)arow * 128 + kg * 8;
    f32x4 acc0 = {0.f, 0.f, 0.f, 0.f};
    f32x4 acc1 = acc0, acc2 = acc0, acc3 = acc0;
#pragma unroll
    for (int ks = 0; ks < 4; ++ks) {
        int k0 = ks * 32;
        float4 xa = *(const float4*)(xr + k0);
        float4 xb = *(const float4*)(xr + k0 + 4);
        bf16x8 a;
        a[0] = (short)f2bf(xa.x); a[1] = (short)f2bf(xa.y);
        a[2] = (short)f2bf(xa.z); a[3] = (short)f2bf(xa.w);
        a[4] = (short)f2bf(xb.x); a[5] = (short)f2bf(xb.y);
        a[6] = (short)f2bf(xb.z); a[7] = (short)f2bf(xb.w);
        const ushort* wb = Wt + (size_t)nl * 128 + k0 + kg * 8;
        bf16x8 b0 = *(const bf16x8*)(wb);
        bf16x8 b1 = *(const bf16x8*)(wb + 16 * 128);
        bf16x8 b2 = *(const bf16x8*)(wb + 32 * 128);
        bf16x8 b3 = *(const bf16x8*)(wb + 48 * 128);
        acc0 = __builtin_amdgcn_mfma_f32_16x16x32_bf16(a, b0, acc0, 0, 0, 0);
        acc1 = __builtin_amdgcn_mfma_f32_16x16x32_bf16(a, b1, acc1, 0, 0, 0);
        acc2 = __builtin_amdgcn_mfma_f32_16x16x32_bf16(a, b2, acc2, 0, 0, 0);
        acc3 = __builtin_amdgcn_mfma_f32_16x16x32_bf16(a, b3, acc3, 0, 0, 0);
    }
#pragma unroll
    for (int r = 0; r < 4; ++r) {
        int row = rowbase + kg * 4 + r;
        if (row < n) {
            float di = dinv[row];
            ushort* out = T1 + (size_t)row * FEAT + nl;
            out[0]  = f2bf(acc0[r] * di);
            out[16] = f2bf(acc1[r] * di);
            out[32] = f2bf(acc2[r] * di);
            out[48] = f2bf(acc3[r] * di);
        }
    }
}

// ---------------- fused CSR-rebuild + aggregation ----------------
// Block = one 256-node bucket, 1024 threads (16 waves). Prologue rebuilds the
// bucket's node-level CSR in LDS from bpk (count -> scan -> scatter); this
// VALU/LDS work hides under the gather-service stalls of the main loop.
// Wave w aggregates local nodes {w, w+16, ...}: 64 lanes = 64 feats, 8-deep
// unrolled 128B gathers, dst scaling from LDS-derived degree.
template<int MODE>
__global__ __launch_bounds__(AGG_TPB) void agg_kernel(const ushort* __restrict__ T,
                                                      const uint* __restrict__ bpk,
                                                      const int* __restrict__ bbase,
                                                      const float* __restrict__ bias,
                                                      ushort* __restrict__ Tout, int n) {
    __shared__ int lsrc[ECAP];
    __shared__ int cnt[BN];
    __shared__ int cur[BN];
    __shared__ int sc[BN];
    int b = blockIdx.x;
    int base = b * BN;
    int t = threadIdx.x;
    int beg = bbase[b], end = bbase[b + 1];
    if (t < BN) cnt[t] = 0;
    __syncthreads();
    for (int p = beg + t; p < end; p += AGG_TPB)
        atomicAdd(&cnt[(bpk[p] >> 17) & 255], 1);
    __syncthreads();
    if (t < BN) sc[t] = cnt[t];
    __syncthreads();
    for (int off = 1; off < BN; off <<= 1) {
        int u = 0;
        if (t < BN && t >= off) u = sc[t - off];
        __syncthreads();
        if (t < BN) sc[t] += u;               // inclusive scan
        __syncthreads();
    }
    if (t < BN) cur[t] = sc[t] - cnt[t];      // exclusive = write cursor
    __syncthreads();
    for (int p = beg + t; p < end; p += AGG_TPB) {
        uint e = bpk[p];
        int pos = atomicAdd(&cur[(e >> 17) & 255], 1);
        lsrc[pos] = (int)(e & 0x1FFFFu);
    }
    __syncthreads();
    int f = t & 63;
    int w = t >> 6;
    for (int nl = w; nl < BN; nl += 16) {
        int node = base + nl;
        if (node >= n) break;                 // only last bucket; no barriers below
        int c = cnt[nl];
        int pe = sc[nl];
        int p = pe - c;
        float acc = bf2f(T[(size_t)node * FEAT + f]);   // self-loop term
        for (; p + 8 <= pe; p += 8) {
            int s0 = lsrc[p],     s1 = lsrc[p + 1], s2 = lsrc[p + 2], s3 = lsrc[p + 3];
            int s4 = lsrc[p + 4], s5 = lsrc[p + 5], s6 = lsrc[p + 6], s7 = lsrc[p + 7];
            float v0 = bf2f(T[(size_t)s0 * FEAT + f]);
            float v1 = bf2f(T[(size_t)s1 * FEAT + f]);
            float v2 = bf2f(T[(size_t)s2 * FEAT + f]);
            float v3 = bf2f(T[(size_t)s3 * FEAT + f]);
            float v4 = bf2f(T[(size_t)s4 * FEAT + f]);
            float v5 = bf2f(T[(size_t)s5 * FEAT + f]);
            float v6 = bf2f(T[(size_t)s6 * FEAT + f]);
            float v7 = bf2f(T[(size_t)s7 * FEAT + f]);
            acc += ((v0 + v1) + (v2 + v3)) + ((v4 + v5) + (v6 + v7));
        }
        for (; p < pe; ++p) acc += bf2f(T[(size_t)lsrc[p] * FEAT + f]);
        float di = rsqrtf((float)c + 1.0f);
        if (MODE == 0) {
            float h = fmaf(di, acc, bias[f]);
            h = fmaxf(h, 0.0f);
            Tout[(size_t)node * FEAT + f] = f2bf(h * di);
        } else {
            Tout[(size_t)node * FEAT + f] = f2bf(di * acc);
        }
    }
}

// ---------------- MFMA dual head: mu/ls = H@W + b (H bf16) ----------------
__global__ __launch_bounds__(256) void gemm_dual_kernel(const ushort* __restrict__ H,
                                                        const ushort* __restrict__ Wmt,
                                                        const float* __restrict__ bmu,
                                                        const ushort* __restrict__ Wlt,
                                                        const float* __restrict__ bls,
                                                        float* __restrict__ mu,
                                                        float* __restrict__ ls, int n) {
    int lane = threadIdx.x & 63;
    int w = threadIdx.x >> 6;
    int rowbase = blockIdx.x * 64 + w * 16;
    int nl = lane & 15;
    int kg = lane >> 4;
    int arow = min(rowbase + nl, n - 1);
    const ushort* hr = H + (size_t)arow * 64 + kg * 8;
    f32x4 am0 = {0.f, 0.f, 0.f, 0.f};
    f32x4 am1 = am0, am2 = am0, am3 = am0;
    f32x4 al0 = am0, al1 = am0, al2 = am0, al3 = am0;
#pragma unroll
    for (int ks = 0; ks < 2; ++ks) {
        int k0 = ks * 32;
        bf16x8 a = *(const bf16x8*)(hr + k0);
        const ushort* wm = Wmt + (size_t)nl * 64 + k0 + kg * 8;
        const ushort* wl = Wlt + (size_t)nl * 64 + k0 + kg * 8;
        bf16x8 m0 = *(const bf16x8*)(wm);
        bf16x8 m1 = *(const bf16x8*)(wm + 16 * 64);
        bf16x8 m2 = *(const bf16x8*)(wm + 32 * 64);
        bf16x8 m3 = *(const bf16x8*)(wm + 48 * 64);
        bf16x8 l0 = *(const bf16x8*)(wl);
        bf16x8 l1 = *(const bf16x8*)(wl + 16 * 64);
        bf16x8 l2 = *(const bf16x8*)(wl + 32 * 64);
        bf16x8 l3 = *(const bf16x8*)(wl + 48 * 64);
        am0 = __builtin_amdgcn_mfma_f32_16x16x32_bf16(a, m0, am0, 0, 0, 0);
        am1 = __builtin_amdgcn_mfma_f32_16x16x32_bf16(a, m1, am1, 0, 0, 0);
        am2 = __builtin_amdgcn_mfma_f32_16x16x32_bf16(a, m2, am2, 0, 0, 0);
        am3 = __builtin_amdgcn_mfma_f32_16x16x32_bf16(a, m3, am3, 0, 0, 0);
        al0 = __builtin_amdgcn_mfma_f32_16x16x32_bf16(a, l0, al0, 0, 0, 0);
        al1 = __builtin_amdgcn_mfma_f32_16x16x32_bf16(a, l1, al1, 0, 0, 0);
        al2 = __builtin_amdgcn_mfma_f32_16x16x32_bf16(a, l2, al2, 0, 0, 0);
        al3 = __builtin_amdgcn_mfma_f32_16x16x32_bf16(a, l3, al3, 0, 0, 0);
    }
    float bm0 = bmu[nl], bm1 = bmu[16 + nl], bm2 = bmu[32 + nl], bm3 = bmu[48 + nl];
    float bl0 = bls[nl], bl1 = bls[16 + nl], bl2 = bls[32 + nl], bl3 = bls[48 + nl];
#pragma unroll
    for (int r = 0; r < 4; ++r) {
        int row = rowbase + kg * 4 + r;
        if (row < n) {
            float* om = mu + (size_t)row * 64 + nl;
            float* ol = ls + (size_t)row * 64 + nl;
            om[0]  = am0[r] + bm0; om[16] = am1[r] + bm1;
            om[32] = am2[r] + bm2; om[48] = am3[r] + bm3;
            ol[0]  = al0[r] + bl0; ol[16] = al1[r] + bl1;
            ol[32] = al2[r] + bl2; ol[48] = al3[r] + bl3;
        }
    }
}

extern "C" void kernel_launch(void* const* d_in, const int* in_sizes, int n_in,
                              void* d_out, int out_size, void* d_ws, size_t ws_size,
                              hipStream_t stream) {
    const float* x   = (const float*)d_in[0];
    const int*   ei  = (const int*)d_in[1];
    const float* W1  = (const float*)d_in[2];
    const float* b1  = (const float*)d_in[3];
    const float* Wmu = (const float*)d_in[4];
    const float* bmu = (const float*)d_in[5];
    const float* Wls = (const float*)d_in[6];
    const float* bls = (const float*)d_in[7];

    const int N = in_sizes[0] / 128;
    const int E = in_sizes[1] / 2;
    const int* src = ei;
    const int* dst = ei + E;

    const int nb = (N + BN - 1) / BN;   // 391 buckets (<= NB_MAX)

    int*    deg    = (int*)d_ws;                        // N
    float*  dinv   = (float*)(deg + N);                 // N
    int*    hist   = (int*)(dinv + N);                  // SORT_BLOCKS*nb
    int*    btot   = hist + SORT_BLOCKS * nb;           // nb (padded)
    int*    bbase  = btot + ((nb + 63) & ~63);          // nb+1 (padded)
    uint*   bpk    = (uint*)(bbase + ((nb + 1 + 63) & ~63)); // E
    ushort* T1     = (ushort*)(bpk + E);                // N*64 bf16 (T1, then T3)
    ushort* T2     = T1 + (size_t)N * FEAT;             // N*64 bf16
    ushort* w1t    = T2 + (size_t)N * FEAT;             // 64*128 bf16
    ushort* wmt    = w1t + 64 * 128;                    // 64*64 bf16
    ushort* wlt    = wmt + 64 * 64;                     // 64*64 bf16

    float* mu_out = (float*)d_out;                      // N*64
    float* ls_out = mu_out + (size_t)N * FEAT;          // N*64

    const int TB = 256;
    int grid_n = (N + TB - 1) / TB;
    int grid_g = (N + 63) / 64;

    // ---- weight prep (independent of everything) ----
    prep_w_kernel<<<8, TB, 0, stream>>>(W1, Wmu, Wls, w1t, wmt, wlt);

    // ---- bucket sort + degrees (no global cursor atomics) ----
    hipMemsetAsync(deg, 0, (size_t)N * sizeof(int), stream);
    hist_kernel<<<SORT_BLOCKS, TB, 0, stream>>>(dst, hist, deg, E, nb);
    dinv_kernel<<<grid_n, TB, 0, stream>>>(deg, dinv, N);
    colscan_kernel<<<nb, TB, 0, stream>>>(hist, btot, nb);
    bbase_kernel<<<1, TB, 0, stream>>>(btot, bbase, nb);
    sort_scatter_kernel<<<SORT_BLOCKS, TB, 0, stream>>>(src, dst, hist, bbase, bpk, E, nb);

    // ---- T1 = bf16(dinv * (x@W1)) via MFMA ----
    gemm1_kernel<<<grid_g, TB, 0, stream>>>(x, w1t, dinv, T1, N);

    // ---- T2 = bf16(dinv * relu(dinv*aggsum(T1) + b1)) ----
    agg_kernel<0><<<nb, AGG_TPB, 0, stream>>>(T1, bpk, bbase, b1, T2, N);

    // ---- T3 = bf16(dinv * aggsum(T2))  (reuses T1 buffer) ----
    agg_kernel<1><<<nb, AGG_TPB, 0, stream>>>(T2, bpk, bbase, nullptr, T1, N);

    // ---- heads via MFMA: mu/ls from bf16 T3 ----
    gemm_dual_kernel<<<grid_g, TB, 0, stream>>>(T1, wmt, bmu, wlt, bls, mu_out, ls_out, N);
}

// Round 12
// 196.617 us; speedup vs baseline: 1.2861x; 1.2861x over previous
//
#include <hip/hip_runtime.h>

// GCN encoder, CSR-free aggregation with separable norm + bf16 gather tables.
//   dinv[i] = rsqrt(deg_in[i]+1)
//   T1 = bf16( dinv * (x@W1) )                       [MFMA gemm1, fused scale+quant]
//   T2 = bf16( dinv * relu( dinv*aggsum(T1) + b1 ) ) [agg<0>]
//   T3 = bf16( dinv * aggsum(T2) )                   [agg<1>, reuses T1 buffer]
//   mu = T3@Wmu+bmu ; ls = T3@Wls+bls                [MFMA dual gemm]
// Edges bucket-sorted (256-node buckets) into bpk; each agg block owns one
// bucket and rebuilds its node-level CSR in LDS (hidden under gather stalls).
// dinv comes from a per-bucket count over bpk (zero atomics) -- R11 lesson:
// random global RMW fused into a narrow-grid kernel serializes (67us hist).
// Lessons kept: no global-cursor atomics (R4), no interleaved slices (R7),
// no cooperative mega-kernel (R9), 64B sort regions (R3).
// aggs are at the compulsory fabric floor (~86MB = 8 XCDs x table once).

using uint = unsigned int;

static constexpr int FEAT = 64;
static constexpr int BN = 256;          // nodes per bucket (dlocal = 8 bits)
static constexpr int SORT_BLOCKS = 256; // edge chunks (keeps 64B sort regions)
static constexpr int NB_MAX = 512;      // max buckets supported in LDS
static constexpr int AGG_TPB = 1024;    // agg block = 16 waves
static constexpr int ECAP = 5120;       // bucket edge cap (mean 4096 + 16 sigma)

typedef __attribute__((ext_vector_type(8))) short bf16x8;
typedef __attribute__((ext_vector_type(4))) float f32x4;

static __device__ __forceinline__ ushort f2bf(float f) {
    uint u = __float_as_uint(f);
    u += 0x7FFFu + ((u >> 16) & 1u);
    return (ushort)(u >> 16);
}
static __device__ __forceinline__ float bf2f(ushort b) {
    return __uint_as_float(((uint)b) << 16);
}

// ---------------- bucket sort ----------------

__global__ __launch_bounds__(256) void hist_kernel(const int* __restrict__ dst,
                                                   int* __restrict__ hist, int E, int nb) {
    __shared__ int h[NB_MAX];
    for (int i = threadIdx.x; i < nb; i += 256) h[i] = 0;
    __syncthreads();
    int chunk = (E + SORT_BLOCKS - 1) / SORT_BLOCKS;
    int beg = blockIdx.x * chunk;
    int end = min(beg + chunk, E);
    for (int e = beg + (int)threadIdx.x; e < end; e += 256)
        atomicAdd(&h[dst[e] >> 8], 1);
    __syncthreads();
    for (int i = threadIdx.x; i < nb; i += 256) hist[blockIdx.x * nb + i] = h[i];
}

__global__ __launch_bounds__(256) void colscan_kernel(int* __restrict__ hist,
                                                      int* __restrict__ btot, int nb) {
    __shared__ int s[256];
    int b = blockIdx.x;
    int t = threadIdx.x;
    int v = hist[t * nb + b];
    s[t] = v; __syncthreads();
    for (int off = 1; off < 256; off <<= 1) {
        int u = (t >= off) ? s[t - off] : 0;
        __syncthreads();
        s[t] += u;
        __syncthreads();
    }
    hist[t * nb + b] = s[t] - v;      // exclusive within bucket
    if (t == 255) btot[b] = s[255];
}

__global__ __launch_bounds__(256) void bbase_kernel(const int* __restrict__ btot,
                                                    int* __restrict__ bbase, int nb) {
    __shared__ int s[256];
    int t = threadIdx.x;
    int i0 = 2 * t, i1 = 2 * t + 1;
    int v0 = (i0 < nb) ? btot[i0] : 0;
    int v1 = (i1 < nb) ? btot[i1] : 0;
    s[t] = v0 + v1; __syncthreads();
    for (int off = 1; off < 256; off <<= 1) {
        int u = (t >= off) ? s[t - off] : 0;
        __syncthreads();
        s[t] += u;
        __syncthreads();
    }
    int excl = s[t] - (v0 + v1);
    if (i0 <= nb) bbase[i0] = excl;
    if (i1 <= nb) bbase[i1] = excl + v0;
}

__global__ __launch_bounds__(256) void sort_scatter_kernel(const int* __restrict__ src,
                                                           const int* __restrict__ dst,
                                                           const int* __restrict__ hist,
                                                           const int* __restrict__ bbase,
                                                           uint* __restrict__ bpk, int E, int nb) {
    __shared__ int cur[NB_MAX];
    int k = blockIdx.x;
    for (int i = threadIdx.x; i < nb; i += 256) cur[i] = bbase[i] + hist[k * nb + i];
    __syncthreads();
    int chunk = (E + SORT_BLOCKS - 1) / SORT_BLOCKS;
    int beg = k * chunk;
    int end = min(beg + chunk, E);
    for (int e = beg + (int)threadIdx.x; e < end; e += 256) {
        int s = src[e], d = dst[e];
        int pos = atomicAdd(&cur[d >> 8], 1);
        bpk[pos] = (uint)s | ((uint)(d & 255) << 17);
    }
}

// dinv from the sorted stream: one block per bucket, LDS count, zero atomics
// beyond LDS. Streaming 6.4MB read.
__global__ __launch_bounds__(256) void dinv_bpk_kernel(const uint* __restrict__ bpk,
                                                       const int* __restrict__ bbase,
                                                       float* __restrict__ dinv, int n) {
    __shared__ int cnt[BN];
    int b = blockIdx.x;
    int base = b * BN;
    int t = threadIdx.x;
    int beg = bbase[b], end = bbase[b + 1];
    cnt[t] = 0;
    __syncthreads();
    for (int p = beg + t; p < end; p += 256)
        atomicAdd(&cnt[(bpk[p] >> 17) & 255], 1);
    __syncthreads();
    int node = base + t;
    if (node < n) dinv[node] = rsqrtf((float)cnt[t] + 1.0f);
}

// ---------------- weight prep: transpose + bf16 ----------------
__global__ __launch_bounds__(256) void prep_w_kernel(const float* __restrict__ W1,
                                                     const float* __restrict__ Wmu,
                                                     const float* __restrict__ Wls,
                                                     ushort* __restrict__ w1t,
                                                     ushort* __restrict__ wmt,
                                                     ushort* __restrict__ wlt) {
    int t = blockIdx.x * 256 + threadIdx.x;
    for (int idx = t; idx < 64 * 128; idx += 2048) {
        int nn = idx >> 7, kk = idx & 127;
        w1t[idx] = f2bf(W1[kk * 64 + nn]);
    }
    for (int idx = t; idx < 64 * 64; idx += 2048) {
        int nn = idx >> 6, kk = idx & 63;
        wmt[idx] = f2bf(Wmu[kk * 64 + nn]);
        wlt[idx] = f2bf(Wls[kk * 64 + nn]);
    }
}

// ---------------- MFMA gemm1: T1 = bf16(dinv * (X@W1)) ----------------
__global__ __launch_bounds__(256) void gemm1_kernel(const float* __restrict__ X,
                                                    const ushort* __restrict__ Wt,
                                                    const float* __restrict__ dinv,
                                                    ushort* __restrict__ T1, int n) {
    int lane = threadIdx.x & 63;
    int w = threadIdx.x >> 6;
    int rowbase = blockIdx.x * 64 + w * 16;
    int nl = lane & 15;
    int kg = lane >> 4;
    int arow = min(rowbase + nl, n - 1);
    const float* xr = X + (size_t)arow * 128 + kg * 8;
    f32x4 acc0 = {0.f, 0.f, 0.f, 0.f};
    f32x4 acc1 = acc0, acc2 = acc0, acc3 = acc0;
#pragma unroll
    for (int ks = 0; ks < 4; ++ks) {
        int k0 = ks * 32;
        float4 xa = *(const float4*)(xr + k0);
        float4 xb = *(const float4*)(xr + k0 + 4);
        bf16x8 a;
        a[0] = (short)f2bf(xa.x); a[1] = (short)f2bf(xa.y);
        a[2] = (short)f2bf(xa.z); a[3] = (short)f2bf(xa.w);
        a[4] = (short)f2bf(xb.x); a[5] = (short)f2bf(xb.y);
        a[6] = (short)f2bf(xb.z); a[7] = (short)f2bf(xb.w);
        const ushort* wb = Wt + (size_t)nl * 128 + k0 + kg * 8;
        bf16x8 b0 = *(const bf16x8*)(wb);
        bf16x8 b1 = *(const bf16x8*)(wb + 16 * 128);
        bf16x8 b2 = *(const bf16x8*)(wb + 32 * 128);
        bf16x8 b3 = *(const bf16x8*)(wb + 48 * 128);
        acc0 = __builtin_amdgcn_mfma_f32_16x16x32_bf16(a, b0, acc0, 0, 0, 0);
        acc1 = __builtin_amdgcn_mfma_f32_16x16x32_bf16(a, b1, acc1, 0, 0, 0);
        acc2 = __builtin_amdgcn_mfma_f32_16x16x32_bf16(a, b2, acc2, 0, 0, 0);
        acc3 = __builtin_amdgcn_mfma_f32_16x16x32_bf16(a, b3, acc3, 0, 0, 0);
    }
#pragma unroll
    for (int r = 0; r < 4; ++r) {
        int row = rowbase + kg * 4 + r;
        if (row < n) {
            float di = dinv[row];
            ushort* out = T1 + (size_t)row * FEAT + nl;
            out[0]  = f2bf(acc0[r] * di);
            out[16] = f2bf(acc1[r] * di);
            out[32] = f2bf(acc2[r] * di);
            out[48] = f2bf(acc3[r] * di);
        }
    }
}

// ---------------- fused CSR-rebuild + aggregation ----------------
template<int MODE>
__global__ __launch_bounds__(AGG_TPB) void agg_kernel(const ushort* __restrict__ T,
                                                      const uint* __restrict__ bpk,
                                                      const int* __restrict__ bbase,
                                                      const float* __restrict__ bias,
                                                      ushort* __restrict__ Tout, int n) {
    __shared__ int lsrc[ECAP];
    __shared__ int cnt[BN];
    __shared__ int cur[BN];
    __shared__ int sc[BN];
    int b = blockIdx.x;
    int base = b * BN;
    int t = threadIdx.x;
    int beg = bbase[b], end = bbase[b + 1];
    if (t < BN) cnt[t] = 0;
    __syncthreads();
    for (int p = beg + t; p < end; p += AGG_TPB)
        atomicAdd(&cnt[(bpk[p] >> 17) & 255], 1);
    __syncthreads();
    if (t < BN) sc[t] = cnt[t];
    __syncthreads();
    for (int off = 1; off < BN; off <<= 1) {
        int u = 0;
        if (t < BN && t >= off) u = sc[t - off];
        __syncthreads();
        if (t < BN) sc[t] += u;               // inclusive scan
        __syncthreads();
    }
    if (t < BN) cur[t] = sc[t] - cnt[t];      // exclusive = write cursor
    __syncthreads();
    for (int p = beg + t; p < end; p += AGG_TPB) {
        uint e = bpk[p];
        int pos = atomicAdd(&cur[(e >> 17) & 255], 1);
        lsrc[pos] = (int)(e & 0x1FFFFu);
    }
    __syncthreads();
    int f = t & 63;
    int w = t >> 6;
    for (int nl = w; nl < BN; nl += 16) {
        int node = base + nl;
        if (node >= n) break;                 // only last bucket; no barriers below
        int c = cnt[nl];
        int pe = sc[nl];
        int p = pe - c;
        float acc = bf2f(T[(size_t)node * FEAT + f]);   // self-loop term
        for (; p + 8 <= pe; p += 8) {
            int s0 = lsrc[p],     s1 = lsrc[p + 1], s2 = lsrc[p + 2], s3 = lsrc[p + 3];
            int s4 = lsrc[p + 4], s5 = lsrc[p + 5], s6 = lsrc[p + 6], s7 = lsrc[p + 7];
            float v0 = bf2f(T[(size_t)s0 * FEAT + f]);
            float v1 = bf2f(T[(size_t)s1 * FEAT + f]);
            float v2 = bf2f(T[(size_t)s2 * FEAT + f]);
            float v3 = bf2f(T[(size_t)s3 * FEAT + f]);
            float v4 = bf2f(T[(size_t)s4 * FEAT + f]);
            float v5 = bf2f(T[(size_t)s5 * FEAT + f]);
            float v6 = bf2f(T[(size_t)s6 * FEAT + f]);
            float v7 = bf2f(T[(size_t)s7 * FEAT + f]);
            acc += ((v0 + v1) + (v2 + v3)) + ((v4 + v5) + (v6 + v7));
        }
        for (; p < pe; ++p) acc += bf2f(T[(size_t)lsrc[p] * FEAT + f]);
        float di = rsqrtf((float)c + 1.0f);
        if (MODE == 0) {
            float h = fmaf(di, acc, bias[f]);
            h = fmaxf(h, 0.0f);
            Tout[(size_t)node * FEAT + f] = f2bf(h * di);
        } else {
            Tout[(size_t)node * FEAT + f] = f2bf(di * acc);
        }
    }
}

// ---------------- MFMA dual head: mu/ls = H@W + b (H bf16) ----------------
__global__ __launch_bounds__(256) void gemm_dual_kernel(const ushort* __restrict__ H,
                                                        const ushort* __restrict__ Wmt,
                                                        const float* __restrict__ bmu,
                                                        const ushort* __restrict__ Wlt,
                                                        const float* __restrict__ bls,
                                                        float* __restrict__ mu,
                                                        float* __restrict__ ls, int n) {
    int lane = threadIdx.x & 63;
    int w = threadIdx.x >> 6;
    int rowbase = blockIdx.x * 64 + w * 16;
    int nl = lane & 15;
    int kg = lane >> 4;
    int arow = min(rowbase + nl, n - 1);
    const ushort* hr = H + (size_t)arow * 64 + kg * 8;
    f32x4 am0 = {0.f, 0.f, 0.f, 0.f};
    f32x4 am1 = am0, am2 = am0, am3 = am0;
    f32x4 al0 = am0, al1 = am0, al2 = am0, al3 = am0;
#pragma unroll
    for (int ks = 0; ks < 2; ++ks) {
        int k0 = ks * 32;
        bf16x8 a = *(const bf16x8*)(hr + k0);
        const ushort* wm = Wmt + (size_t)nl * 64 + k0 + kg * 8;
        const ushort* wl = Wlt + (size_t)nl * 64 + k0 + kg * 8;
        bf16x8 m0 = *(const bf16x8*)(wm);
        bf16x8 m1 = *(const bf16x8*)(wm + 16 * 64);
        bf16x8 m2 = *(const bf16x8*)(wm + 32 * 64);
        bf16x8 m3 = *(const bf16x8*)(wm + 48 * 64);
        bf16x8 l0 = *(const bf16x8*)(wl);
        bf16x8 l1 = *(const bf16x8*)(wl + 16 * 64);
        bf16x8 l2 = *(const bf16x8*)(wl + 32 * 64);
        bf16x8 l3 = *(const bf16x8*)(wl + 48 * 64);
        am0 = __builtin_amdgcn_mfma_f32_16x16x32_bf16(a, m0, am0, 0, 0, 0);
        am1 = __builtin_amdgcn_mfma_f32_16x16x32_bf16(a, m1, am1, 0, 0, 0);
        am2 = __builtin_amdgcn_mfma_f32_16x16x32_bf16(a, m2, am2, 0, 0, 0);
        am3 = __builtin_amdgcn_mfma_f32_16x16x32_bf16(a, m3, am3, 0, 0, 0);
        al0 = __builtin_amdgcn_mfma_f32_16x16x32_bf16(a, l0, al0, 0, 0, 0);
        al1 = __builtin_amdgcn_mfma_f32_16x16x32_bf16(a, l1, al1, 0, 0, 0);
        al2 = __builtin_amdgcn_mfma_f32_16x16x32_bf16(a, l2, al2, 0, 0, 0);
        al3 = __builtin_amdgcn_mfma_f32_16x16x32_bf16(a, l3, al3, 0, 0, 0);
    }
    float bm0 = bmu[nl], bm1 = bmu[16 + nl], bm2 = bmu[32 + nl], bm3 = bmu[48 + nl];
    float bl0 = bls[nl], bl1 = bls[16 + nl], bl2 = bls[32 + nl], bl3 = bls[48 + nl];
#pragma unroll
    for (int r = 0; r < 4; ++r) {
        int row = rowbase + kg * 4 + r;
        if (row < n) {
            float* om = mu + (size_t)row * 64 + nl;
            float* ol = ls + (size_t)row * 64 + nl;
            om[0]  = am0[r] + bm0; om[16] = am1[r] + bm1;
            om[32] = am2[r] + bm2; om[48] = am3[r] + bm3;
            ol[0]  = al0[r] + bl0; ol[16] = al1[r] + bl1;
            ol[32] = al2[r] + bl2; ol[48] = al3[r] + bl3;
        }
    }
}

extern "C" void kernel_launch(void* const* d_in, const int* in_sizes, int n_in,
                              void* d_out, int out_size, void* d_ws, size_t ws_size,
                              hipStream_t stream) {
    const float* x   = (const float*)d_in[0];
    const int*   ei  = (const int*)d_in[1];
    const float* W1  = (const float*)d_in[2];
    const float* b1  = (const float*)d_in[3];
    const float* Wmu = (const float*)d_in[4];
    const float* bmu = (const float*)d_in[5];
    const float* Wls = (const float*)d_in[6];
    const float* bls = (const float*)d_in[7];

    const int N = in_sizes[0] / 128;
    const int E = in_sizes[1] / 2;
    const int* src = ei;
    const int* dst = ei + E;

    const int nb = (N + BN - 1) / BN;   // 391 buckets (<= NB_MAX)

    float*  dinv   = (float*)d_ws;                      // N
    int*    hist   = (int*)(dinv + N);                  // SORT_BLOCKS*nb
    int*    btot   = hist + SORT_BLOCKS * nb;           // nb (padded)
    int*    bbase  = btot + ((nb + 63) & ~63);          // nb+1 (padded)
    uint*   bpk    = (uint*)(bbase + ((nb + 1 + 63) & ~63)); // E
    ushort* T1     = (ushort*)(bpk + E);                // N*64 bf16 (T1, then T3)
    ushort* T2     = T1 + (size_t)N * FEAT;             // N*64 bf16
    ushort* w1t    = T2 + (size_t)N * FEAT;             // 64*128 bf16
    ushort* wmt    = w1t + 64 * 128;                    // 64*64 bf16
    ushort* wlt    = wmt + 64 * 64;                     // 64*64 bf16

    float* mu_out = (float*)d_out;                      // N*64
    float* ls_out = mu_out + (size_t)N * FEAT;          // N*64

    const int TB = 256;
    int grid_g = (N + 63) / 64;

    // ---- weight prep (independent of everything) ----
    prep_w_kernel<<<8, TB, 0, stream>>>(W1, Wmu, Wls, w1t, wmt, wlt);

    // ---- bucket sort (no global atomics) ----
    hist_kernel<<<SORT_BLOCKS, TB, 0, stream>>>(dst, hist, E, nb);
    colscan_kernel<<<nb, TB, 0, stream>>>(hist, btot, nb);
    bbase_kernel<<<1, TB, 0, stream>>>(btot, bbase, nb);
    sort_scatter_kernel<<<SORT_BLOCKS, TB, 0, stream>>>(src, dst, hist, bbase, bpk, E, nb);
    dinv_bpk_kernel<<<nb, TB, 0, stream>>>(bpk, bbase, dinv, N);

    // ---- T1 = bf16(dinv * (x@W1)) via MFMA ----
    gemm1_kernel<<<grid_g, TB, 0, stream>>>(x, w1t, dinv, T1, N);

    // ---- T2 = bf16(dinv * relu(dinv*aggsum(T1) + b1)) ----
    agg_kernel<0><<<nb, AGG_TPB, 0, stream>>>(T1, bpk, bbase, b1, T2, N);

    // ---- T3 = bf16(dinv * aggsum(T2))  (reuses T1 buffer) ----
    agg_kernel<1><<<nb, AGG_TPB, 0, stream>>>(T2, bpk, bbase, nullptr, T1, N);

    // ---- heads via MFMA: mu/ls from bf16 T3 ----
    gemm_dual_kernel<<<grid_g, TB, 0, stream>>>(T1, wmt, bmu, wlt, bls, mu_out, ls_out, N);
}

// Round 13
// 187.836 us; speedup vs baseline: 1.3462x; 1.0467x over previous
//
#include <hip/hip_runtime.h>

// GCN encoder, CSR-free aggregation with separable norm + bf16 gather tables.
//   dinv[i] = rsqrt(deg_in[i]+1)
//   T1 = bf16( dinv * (x@W1) )                       [MFMA gemm1, fused scale+quant]
//   T2 = bf16( dinv * relu( dinv*aggsum(T1) + b1 ) ) [agg<0>]
//   T3 = bf16( dinv * aggsum(T2) )                   [agg<1>, reuses T1 buffer]
//   mu = T3@Wmu+bmu ; ls = T3@Wls+bls                [MFMA dual gemm]
// Edges bucket-sorted (256-node buckets) into bpk; each agg block owns one
// bucket and rebuilds its node-level CSR in LDS (hidden under gather stalls).
// Sort kernels run 16 waves/block (R13): they are latency chains (load ->
// LDS atomic) and 4 waves/CU could not hide it; block count stays 256 so
// per-(block,bucket) regions stay 64B-line-sized (R3 lesson).
// Lessons kept: no global-cursor atomics (R4), no interleaved slices (R7),
// no cooperative mega-kernel (R9), no narrow-grid global RMW (R11).
// aggs are at the compulsory fabric floor (~86MB = 8 XCDs x table once).

using uint = unsigned int;

static constexpr int FEAT = 64;
static constexpr int BN = 256;          // nodes per bucket (dlocal = 8 bits)
static constexpr int SORT_BLOCKS = 256; // edge chunks (keeps 64B sort regions)
static constexpr int SORT_TPB = 1024;   // 16 waves/block for latency hiding
static constexpr int NB_MAX = 512;      // max buckets supported in LDS
static constexpr int AGG_TPB = 1024;    // agg block = 16 waves
static constexpr int ECAP = 5120;       // bucket edge cap (mean 4096 + 16 sigma)

typedef __attribute__((ext_vector_type(8))) short bf16x8;
typedef __attribute__((ext_vector_type(4))) float f32x4;

static __device__ __forceinline__ ushort f2bf(float f) {
    uint u = __float_as_uint(f);
    u += 0x7FFFu + ((u >> 16) & 1u);
    return (ushort)(u >> 16);
}
static __device__ __forceinline__ float bf2f(ushort b) {
    return __uint_as_float(((uint)b) << 16);
}

// ---------------- bucket sort ----------------

__global__ __launch_bounds__(SORT_TPB) void hist_kernel(const int* __restrict__ dst,
                                                        int* __restrict__ hist, int E, int nb) {
    __shared__ int h[NB_MAX];
    for (int i = threadIdx.x; i < nb; i += SORT_TPB) h[i] = 0;
    __syncthreads();
    int chunk = (E + SORT_BLOCKS - 1) / SORT_BLOCKS;
    int beg = blockIdx.x * chunk;
    int end = min(beg + chunk, E);
    for (int e = beg + (int)threadIdx.x; e < end; e += SORT_TPB)
        atomicAdd(&h[dst[e] >> 8], 1);
    __syncthreads();
    for (int i = threadIdx.x; i < nb; i += SORT_TPB) hist[blockIdx.x * nb + i] = h[i];
}

__global__ __launch_bounds__(256) void colscan_kernel(int* __restrict__ hist,
                                                      int* __restrict__ btot, int nb) {
    __shared__ int s[256];
    int b = blockIdx.x;
    int t = threadIdx.x;
    int v = hist[t * nb + b];
    s[t] = v; __syncthreads();
    for (int off = 1; off < 256; off <<= 1) {
        int u = (t >= off) ? s[t - off] : 0;
        __syncthreads();
        s[t] += u;
        __syncthreads();
    }
    hist[t * nb + b] = s[t] - v;      // exclusive within bucket
    if (t == 255) btot[b] = s[255];
}

__global__ __launch_bounds__(256) void bbase_kernel(const int* __restrict__ btot,
                                                    int* __restrict__ bbase, int nb) {
    __shared__ int s[256];
    int t = threadIdx.x;
    int i0 = 2 * t, i1 = 2 * t + 1;
    int v0 = (i0 < nb) ? btot[i0] : 0;
    int v1 = (i1 < nb) ? btot[i1] : 0;
    s[t] = v0 + v1; __syncthreads();
    for (int off = 1; off < 256; off <<= 1) {
        int u = (t >= off) ? s[t - off] : 0;
        __syncthreads();
        s[t] += u;
        __syncthreads();
    }
    int excl = s[t] - (v0 + v1);
    if (i0 <= nb) bbase[i0] = excl;
    if (i1 <= nb) bbase[i1] = excl + v0;
}

__global__ __launch_bounds__(SORT_TPB) void sort_scatter_kernel(const int* __restrict__ src,
                                                                const int* __restrict__ dst,
                                                                const int* __restrict__ hist,
                                                                const int* __restrict__ bbase,
                                                                uint* __restrict__ bpk,
                                                                int E, int nb) {
    __shared__ int cur[NB_MAX];
    int k = blockIdx.x;
    for (int i = threadIdx.x; i < nb; i += SORT_TPB) cur[i] = bbase[i] + hist[k * nb + i];
    __syncthreads();
    int chunk = (E + SORT_BLOCKS - 1) / SORT_BLOCKS;
    int beg = k * chunk;
    int end = min(beg + chunk, E);
    for (int e = beg + (int)threadIdx.x; e < end; e += SORT_TPB) {
        int s = src[e], d = dst[e];
        int pos = atomicAdd(&cur[d >> 8], 1);
        bpk[pos] = (uint)s | ((uint)(d & 255) << 17);
    }
}

// dinv from the sorted stream: one block per bucket, LDS count, zero global atomics.
__global__ __launch_bounds__(SORT_TPB) void dinv_bpk_kernel(const uint* __restrict__ bpk,
                                                            const int* __restrict__ bbase,
                                                            float* __restrict__ dinv, int n) {
    __shared__ int cnt[BN];
    int b = blockIdx.x;
    int base = b * BN;
    int t = threadIdx.x;
    int beg = bbase[b], end = bbase[b + 1];
    if (t < BN) cnt[t] = 0;
    __syncthreads();
    for (int p = beg + t; p < end; p += SORT_TPB)
        atomicAdd(&cnt[(bpk[p] >> 17) & 255], 1);
    __syncthreads();
    int node = base + t;
    if (t < BN && node < n) dinv[node] = rsqrtf((float)cnt[t] + 1.0f);
}

// ---------------- weight prep: transpose + bf16 ----------------
__global__ __launch_bounds__(256) void prep_w_kernel(const float* __restrict__ W1,
                                                     const float* __restrict__ Wmu,
                                                     const float* __restrict__ Wls,
                                                     ushort* __restrict__ w1t,
                                                     ushort* __restrict__ wmt,
                                                     ushort* __restrict__ wlt) {
    int t = blockIdx.x * 256 + threadIdx.x;
    for (int idx = t; idx < 64 * 128; idx += 2048) {
        int nn = idx >> 7, kk = idx & 127;
        w1t[idx] = f2bf(W1[kk * 64 + nn]);
    }
    for (int idx = t; idx < 64 * 64; idx += 2048) {
        int nn = idx >> 6, kk = idx & 63;
        wmt[idx] = f2bf(Wmu[kk * 64 + nn]);
        wlt[idx] = f2bf(Wls[kk * 64 + nn]);
    }
}

// ---------------- MFMA gemm1: T1 = bf16(dinv * (X@W1)) ----------------
__global__ __launch_bounds__(256) void gemm1_kernel(const float* __restrict__ X,
                                                    const ushort* __restrict__ Wt,
                                                    const float* __restrict__ dinv,
                                                    ushort* __restrict__ T1, int n) {
    int lane = threadIdx.x & 63;
    int w = threadIdx.x >> 6;
    int rowbase = blockIdx.x * 64 + w * 16;
    int nl = lane & 15;
    int kg = lane >> 4;
    int arow = min(rowbase + nl, n - 1);
    const float* xr = X + (size_t)arow * 128 + kg * 8;
    f32x4 acc0 = {0.f, 0.f, 0.f, 0.f};
    f32x4 acc1 = acc0, acc2 = acc0, acc3 = acc0;
#pragma unroll
    for (int ks = 0; ks < 4; ++ks) {
        int k0 = ks * 32;
        float4 xa = *(const float4*)(xr + k0);
        float4 xb = *(const float4*)(xr + k0 + 4);
        bf16x8 a;
        a[0] = (short)f2bf(xa.x); a[1] = (short)f2bf(xa.y);
        a[2] = (short)f2bf(xa.z); a[3] = (short)f2bf(xa.w);
        a[4] = (short)f2bf(xb.x); a[5] = (short)f2bf(xb.y);
        a[6] = (short)f2bf(xb.z); a[7] = (short)f2bf(xb.w);
        const ushort* wb = Wt + (size_t)nl * 128 + k0 + kg * 8;
        bf16x8 b0 = *(const bf16x8*)(wb);
        bf16x8 b1 = *(const bf16x8*)(wb + 16 * 128);
        bf16x8 b2 = *(const bf16x8*)(wb + 32 * 128);
        bf16x8 b3 = *(const bf16x8*)(wb + 48 * 128);
        acc0 = __builtin_amdgcn_mfma_f32_16x16x32_bf16(a, b0, acc0, 0, 0, 0);
        acc1 = __builtin_amdgcn_mfma_f32_16x16x32_bf16(a, b1, acc1, 0, 0, 0);
        acc2 = __builtin_amdgcn_mfma_f32_16x16x32_bf16(a, b2, acc2, 0, 0, 0);
        acc3 = __builtin_amdgcn_mfma_f32_16x16x32_bf16(a, b3, acc3, 0, 0, 0);
    }
#pragma unroll
    for (int r = 0; r < 4; ++r) {
        int row = rowbase + kg * 4 + r;
        if (row < n) {
            float di = dinv[row];
            ushort* out = T1 + (size_t)row * FEAT + nl;
            out[0]  = f2bf(acc0[r] * di);
            out[16] = f2bf(acc1[r] * di);
            out[32] = f2bf(acc2[r] * di);
            out[48] = f2bf(acc3[r] * di);
        }
    }
}

// ---------------- fused CSR-rebuild + aggregation ----------------
template<int MODE>
__global__ __launch_bounds__(AGG_TPB) void agg_kernel(const ushort* __restrict__ T,
                                                      const uint* __restrict__ bpk,
                                                      const int* __restrict__ bbase,
                                                      const float* __restrict__ bias,
                                                      ushort* __restrict__ Tout, int n) {
    __shared__ int lsrc[ECAP];
    __shared__ int cnt[BN];
    __shared__ int cur[BN];
    __shared__ int sc[BN];
    int b = blockIdx.x;
    int base = b * BN;
    int t = threadIdx.x;
    int beg = bbase[b], end = bbase[b + 1];
    if (t < BN) cnt[t] = 0;
    __syncthreads();
    for (int p = beg + t; p < end; p += AGG_TPB)
        atomicAdd(&cnt[(bpk[p] >> 17) & 255], 1);
    __syncthreads();
    if (t < BN) sc[t] = cnt[t];
    __syncthreads();
    for (int off = 1; off < BN; off <<= 1) {
        int u = 0;
        if (t < BN && t >= off) u = sc[t - off];
        __syncthreads();
        if (t < BN) sc[t] += u;               // inclusive scan
        __syncthreads();
    }
    if (t < BN) cur[t] = sc[t] - cnt[t];      // exclusive = write cursor
    __syncthreads();
    for (int p = beg + t; p < end; p += AGG_TPB) {
        uint e = bpk[p];
        int pos = atomicAdd(&cur[(e >> 17) & 255], 1);
        lsrc[pos] = (int)(e & 0x1FFFFu);
    }
    __syncthreads();
    int f = t & 63;
    int w = t >> 6;
    for (int nl = w; nl < BN; nl += 16) {
        int node = base + nl;
        if (node >= n) break;                 // only last bucket; no barriers below
        int c = cnt[nl];
        int pe = sc[nl];
        int p = pe - c;
        float acc = bf2f(T[(size_t)node * FEAT + f]);   // self-loop term
        for (; p + 8 <= pe; p += 8) {
            int s0 = lsrc[p],     s1 = lsrc[p + 1], s2 = lsrc[p + 2], s3 = lsrc[p + 3];
            int s4 = lsrc[p + 4], s5 = lsrc[p + 5], s6 = lsrc[p + 6], s7 = lsrc[p + 7];
            float v0 = bf2f(T[(size_t)s0 * FEAT + f]);
            float v1 = bf2f(T[(size_t)s1 * FEAT + f]);
            float v2 = bf2f(T[(size_t)s2 * FEAT + f]);
            float v3 = bf2f(T[(size_t)s3 * FEAT + f]);
            float v4 = bf2f(T[(size_t)s4 * FEAT + f]);
            float v5 = bf2f(T[(size_t)s5 * FEAT + f]);
            float v6 = bf2f(T[(size_t)s6 * FEAT + f]);
            float v7 = bf2f(T[(size_t)s7 * FEAT + f]);
            acc += ((v0 + v1) + (v2 + v3)) + ((v4 + v5) + (v6 + v7));
        }
        for (; p < pe; ++p) acc += bf2f(T[(size_t)lsrc[p] * FEAT + f]);
        float di = rsqrtf((float)c + 1.0f);
        if (MODE == 0) {
            float h = fmaf(di, acc, bias[f]);
            h = fmaxf(h, 0.0f);
            Tout[(size_t)node * FEAT + f] = f2bf(h * di);
        } else {
            Tout[(size_t)node * FEAT + f] = f2bf(di * acc);
        }
    }
}

// ---------------- MFMA dual head: mu/ls = H@W + b (H bf16) ----------------
__global__ __launch_bounds__(256) void gemm_dual_kernel(const ushort* __restrict__ H,
                                                        const ushort* __restrict__ Wmt,
                                                        const float* __restrict__ bmu,
                                                        const ushort* __restrict__ Wlt,
                                                        const float* __restrict__ bls,
                                                        float* __restrict__ mu,
                                                        float* __restrict__ ls, int n) {
    int lane = threadIdx.x & 63;
    int w = threadIdx.x >> 6;
    int rowbase = blockIdx.x * 64 + w * 16;
    int nl = lane & 15;
    int kg = lane >> 4;
    int arow = min(rowbase + nl, n - 1);
    const ushort* hr = H + (size_t)arow * 64 + kg * 8;
    f32x4 am0 = {0.f, 0.f, 0.f, 0.f};
    f32x4 am1 = am0, am2 = am0, am3 = am0;
    f32x4 al0 = am0, al1 = am0, al2 = am0, al3 = am0;
#pragma unroll
    for (int ks = 0; ks < 2; ++ks) {
        int k0 = ks * 32;
        bf16x8 a = *(const bf16x8*)(hr + k0);
        const ushort* wm = Wmt + (size_t)nl * 64 + k0 + kg * 8;
        const ushort* wl = Wlt + (size_t)nl * 64 + k0 + kg * 8;
        bf16x8 m0 = *(const bf16x8*)(wm);
        bf16x8 m1 = *(const bf16x8*)(wm + 16 * 64);
        bf16x8 m2 = *(const bf16x8*)(wm + 32 * 64);
        bf16x8 m3 = *(const bf16x8*)(wm + 48 * 64);
        bf16x8 l0 = *(const bf16x8*)(wl);
        bf16x8 l1 = *(const bf16x8*)(wl + 16 * 64);
        bf16x8 l2 = *(const bf16x8*)(wl + 32 * 64);
        bf16x8 l3 = *(const bf16x8*)(wl + 48 * 64);
        am0 = __builtin_amdgcn_mfma_f32_16x16x32_bf16(a, m0, am0, 0, 0, 0);
        am1 = __builtin_amdgcn_mfma_f32_16x16x32_bf16(a, m1, am1, 0, 0, 0);
        am2 = __builtin_amdgcn_mfma_f32_16x16x32_bf16(a, m2, am2, 0, 0, 0);
        am3 = __builtin_amdgcn_mfma_f32_16x16x32_bf16(a, m3, am3, 0, 0, 0);
        al0 = __builtin_amdgcn_mfma_f32_16x16x32_bf16(a, l0, al0, 0, 0, 0);
        al1 = __builtin_amdgcn_mfma_f32_16x16x32_bf16(a, l1, al1, 0, 0, 0);
        al2 = __builtin_amdgcn_mfma_f32_16x16x32_bf16(a, l2, al2, 0, 0, 0);
        al3 = __builtin_amdgcn_mfma_f32_16x16x32_bf16(a, l3, al3, 0, 0, 0);
    }
    float bm0 = bmu[nl], bm1 = bmu[16 + nl], bm2 = bmu[32 + nl], bm3 = bmu[48 + nl];
    float bl0 = bls[nl], bl1 = bls[16 + nl], bl2 = bls[32 + nl], bl3 = bls[48 + nl];
#pragma unroll
    for (int r = 0; r < 4; ++r) {
        int row = rowbase + kg * 4 + r;
        if (row < n) {
            float* om = mu + (size_t)row * 64 + nl;
            float* ol = ls + (size_t)row * 64 + nl;
            om[0]  = am0[r] + bm0; om[16] = am1[r] + bm1;
            om[32] = am2[r] + bm2; om[48] = am3[r] + bm3;
            ol[0]  = al0[r] + bl0; ol[16] = al1[r] + bl1;
            ol[32] = al2[r] + bl2; ol[48] = al3[r] + bl3;
        }
    }
}

extern "C" void kernel_launch(void* const* d_in, const int* in_sizes, int n_in,
                              void* d_out, int out_size, void* d_ws, size_t ws_size,
                              hipStream_t stream) {
    const float* x   = (const float*)d_in[0];
    const int*   ei  = (const int*)d_in[1];
    const float* W1  = (const float*)d_in[2];
    const float* b1  = (const float*)d_in[3];
    const float* Wmu = (const float*)d_in[4];
    const float* bmu = (const float*)d_in[5];
    const float* Wls = (const float*)d_in[6];
    const float* bls = (const float*)d_in[7];

    const int N = in_sizes[0] / 128;
    const int E = in_sizes[1] / 2;
    const int* src = ei;
    const int* dst = ei + E;

    const int nb = (N + BN - 1) / BN;   // 391 buckets (<= NB_MAX)

    float*  dinv   = (float*)d_ws;                      // N
    int*    hist   = (int*)(dinv + N);                  // SORT_BLOCKS*nb
    int*    btot   = hist + SORT_BLOCKS * nb;           // nb (padded)
    int*    bbase  = btot + ((nb + 63) & ~63);          // nb+1 (padded)
    uint*   bpk    = (uint*)(bbase + ((nb + 1 + 63) & ~63)); // E
    ushort* T1     = (ushort*)(bpk + E);                // N*64 bf16 (T1, then T3)
    ushort* T2     = T1 + (size_t)N * FEAT;             // N*64 bf16
    ushort* w1t    = T2 + (size_t)N * FEAT;             // 64*128 bf16
    ushort* wmt    = w1t + 64 * 128;                    // 64*64 bf16
    ushort* wlt    = wmt + 64 * 64;                     // 64*64 bf16

    float* mu_out = (float*)d_out;                      // N*64
    float* ls_out = mu_out + (size_t)N * FEAT;          // N*64

    const int TB = 256;
    int grid_g = (N + 63) / 64;

    // ---- weight prep (independent of everything) ----
    prep_w_kernel<<<8, TB, 0, stream>>>(W1, Wmu, Wls, w1t, wmt, wlt);

    // ---- bucket sort (no global atomics; 16 waves/block) ----
    hist_kernel<<<SORT_BLOCKS, SORT_TPB, 0, stream>>>(dst, hist, E, nb);
    colscan_kernel<<<nb, TB, 0, stream>>>(hist, btot, nb);
    bbase_kernel<<<1, TB, 0, stream>>>(btot, bbase, nb);
    sort_scatter_kernel<<<SORT_BLOCKS, SORT_TPB, 0, stream>>>(src, dst, hist, bbase, bpk, E, nb);
    dinv_bpk_kernel<<<nb, SORT_TPB, 0, stream>>>(bpk, bbase, dinv, N);

    // ---- T1 = bf16(dinv * (x@W1)) via MFMA ----
    gemm1_kernel<<<grid_g, TB, 0, stream>>>(x, w1t, dinv, T1, N);

    // ---- T2 = bf16(dinv * relu(dinv*aggsum(T1) + b1)) ----
    agg_kernel<0><<<nb, AGG_TPB, 0, stream>>>(T1, bpk, bbase, b1, T2, N);

    // ---- T3 = bf16(dinv * aggsum(T2))  (reuses T1 buffer) ----
    agg_kernel<1><<<nb, AGG_TPB, 0, stream>>>(T2, bpk, bbase, nullptr, T1, N);

    // ---- heads via MFMA: mu/ls from bf16 T3 ----
    gemm_dual_kernel<<<grid_g, TB, 0, stream>>>(T1, wmt, bmu, wlt, bls, mu_out, ls_out, N);
}